// Round 3
// baseline (173.921 us; speedup 1.0000x reference)
//
#include <hip/hip_runtime.h>
#include <stdint.h>

#define M_DIM 2048
#define K_DIM 4096
#define N_DIM 11008

typedef int v4i __attribute__((ext_vector_type(4)));

// ---------------- workspace layout ----------------
#define WS_XQ_OFF   65536ull
#define WS_WT_OFF   8454144ull
#define WS_FULL_BYTES (8454144ull + 45088768ull)
#define WS_SMALL_BYTES 8454144ull

static __device__ __forceinline__ void llds16(const void* g, void* l) {
  __builtin_amdgcn_global_load_lds(
      reinterpret_cast<const uint32_t __attribute__((address_space(1)))*>(
          reinterpret_cast<uintptr_t>(g)),
      reinterpret_cast<uint32_t __attribute__((address_space(3)))*>(
          reinterpret_cast<uintptr_t>(l)),
      16, 0, 0);
}

// ---------------- kernel 1: per-block abs-max over x ----------------
__global__ __launch_bounds__(256) void absmax_kernel(const float* __restrict__ x,
                                                     float* __restrict__ part) {
  __shared__ float red[256];
  const int g = blockIdx.x * 256 + threadIdx.x;
  const float4* x4 = reinterpret_cast<const float4*>(x);
  float m = 0.f;
#pragma unroll
  for (int i = 0; i < 8; ++i) {
    float4 v = x4[(size_t)i * 262144 + g];
    m = fmaxf(m, fmaxf(fmaxf(fabsf(v.x), fabsf(v.y)),
                       fmaxf(fabsf(v.z), fabsf(v.w))));
  }
  red[threadIdx.x] = m;
  __syncthreads();
  for (int s = 128; s > 0; s >>= 1) {
    if (threadIdx.x < s) red[threadIdx.x] = fmaxf(red[threadIdx.x], red[threadIdx.x + s]);
    __syncthreads();
  }
  if (threadIdx.x == 0) part[blockIdx.x] = red[0];
}

// ---------------- kernel 2: finalize scales ----------------
__global__ __launch_bounds__(256) void finalize_scale(const float* __restrict__ part,
                                                      const float* __restrict__ y_scale,
                                                      float* __restrict__ scales) {
  __shared__ float red[256];
  const int t = threadIdx.x;
  float m = fmaxf(fmaxf(part[t], part[t + 256]), fmaxf(part[t + 512], part[t + 768]));
  red[t] = m;
  __syncthreads();
  for (int s = 128; s > 0; s >>= 1) {
    if (t < s) red[t] = fmaxf(red[t], red[t + s]);
    __syncthreads();
  }
  if (t == 0) {
    float xs = red[0] * (1.0f / 128.0f);  // exact (pow2)
    scales[0] = xs;
    scales[1] = xs * y_scale[0];
  }
}

// ---------------- kernel 3: quantize x -> int8 ----------------
__global__ __launch_bounds__(256) void quant_kernel(const float* __restrict__ x,
                                                    const float* __restrict__ scales,
                                                    signed char* __restrict__ xq) {
  const float s = scales[0];
  const size_t t = (size_t)blockIdx.x * 256 + threadIdx.x;
  const float4* x4 = reinterpret_cast<const float4*>(x) + t * 4;
  v4i o;
#pragma unroll
  for (int i = 0; i < 4; ++i) {
    float4 v = x4[i];
    int q0 = (int)rintf(v.x / s);  // matches np.round (half-to-even)
    int q1 = (int)rintf(v.y / s);
    int q2 = (int)rintf(v.z / s);
    int q3 = (int)rintf(v.w / s);
    q0 = max(-128, min(127, q0));
    q1 = max(-128, min(127, q1));
    q2 = max(-128, min(127, q2));
    q3 = max(-128, min(127, q3));
    o[i] = (q0 & 255) | ((q1 & 255) << 8) | ((q2 & 255) << 16) | ((q3 & 255) << 24);
  }
  *reinterpret_cast<v4i*>(xq + t * 16) = o;
}

// ---------------- kernel 4: transpose+pack w32[K,N] -> w_t int8[N,K] ----------------
__global__ __launch_bounds__(256) void transpose_pack(const int* __restrict__ w,
                                                      signed char* __restrict__ wt) {
  __shared__ int tile[64 * 65];
  const int t = threadIdx.x;
  const int n0 = blockIdx.x * 64;
  const int k0 = blockIdx.y * 64;
#pragma unroll
  for (int p = 0; p < 4; ++p) {
    const int id = p * 256 + t;
    const int r = id >> 4;
    const int c4 = id & 15;
    v4i v = *reinterpret_cast<const v4i*>(w + (size_t)(k0 + r) * N_DIM + n0 + c4 * 4);
    tile[r * 65 + c4 * 4 + 0] = v[0];
    tile[r * 65 + c4 * 4 + 1] = v[1];
    tile[r * 65 + c4 * 4 + 2] = v[2];
    tile[r * 65 + c4 * 4 + 3] = v[3];
  }
  __syncthreads();
  const int nl = t >> 2;
  const int kseg = t & 3;
  v4i o;
#pragma unroll
  for (int q = 0; q < 4; ++q) {
    const int kb = kseg * 16 + q * 4;
    int b0 = tile[(kb + 0) * 65 + nl] & 255;
    int b1 = tile[(kb + 1) * 65 + nl] & 255;
    int b2 = tile[(kb + 2) * 65 + nl] & 255;
    int b3 = tile[(kb + 3) * 65 + nl] & 255;
    o[q] = b0 | (b1 << 8) | (b2 << 16) | (b3 << 24);
  }
  *reinterpret_cast<v4i*>(wt + (size_t)(n0 + nl) * K_DIM + k0 + kseg * 16) = o;
}

// ---------------- kernel 5: int8 MFMA GEMM v3 (phase-split 8-wave schedule) ----
// BM=128, BN=256, BK=128 bytes. 512 threads = 8 waves (2M x 4N), per-wave
// 64x64 via 4x4 frags of mfma_i32_16x16x64_i8 (x2 k-steps per K-tile).
// Ring-3 LDS (3 x 48KB = 144KB), depth-2 prefetch, vmcnt(6) once per K-tile,
// per-phase {ds_read || stage-issue -> barrier -> lgkmcnt(0) -> prio1 16xMFMA
// prio0 -> barrier} interleave (T3+T4+T5; regime-gated combo).
#define BKB     128
#define A_BYTES (128 * BKB)              // 16 KB
#define B_BYTES (256 * BKB)              // 32 KB
#define TILE3_B (A_BYTES + B_BYTES)      // 48 KB
#define NT3     (K_DIM / BKB)            // 32 K-tiles

__global__ __launch_bounds__(512, 2) void gemm_i8_v3(
    const signed char* __restrict__ xq, const signed char* __restrict__ wt,
    const float* __restrict__ scales, const float* __restrict__ bias,
    float* __restrict__ y) {
  __shared__ __align__(16) signed char smem[3 * TILE3_B];  // 144 KB
  const int tid = threadIdx.x;

  // T1: bijective XCD swizzle (688 blocks, 688 % 8 == 0), column-major grid
  // so 16 consecutive m-tiles share one 1MB wt n-panel in L2.
  const int bid = blockIdx.x;
  const int swz = (bid & 7) * 86 + (bid >> 3);
  const int m0 = (swz & 15) * 128;
  const int n0 = (swz >> 4) * 256;

  // ---- staging map: thread -> (row = tid>>3, seg = tid&7) of a 128B row.
  // LDS dest linear (tid*16 within each 8KB load-group); XOR involution
  // seg' = seg ^ (row&7) applied on the GLOBAL source (both-sides rule).
  // Row offsets k*64 keep row&7 invariant -> source seg offset k-invariant.
  const int srow = tid >> 3;   // 0..63
  const int sseg = tid & 7;
  const int sgoff = (sseg ^ (srow & 7)) * 16;
  const signed char* gA = xq + (size_t)(m0 + srow) * K_DIM + sgoff;
  const signed char* gB = wt + (size_t)(n0 + srow) * K_DIM + sgoff;
  signed char* const ld = smem + tid * 16;

#define STAGE_P0(kt, soff)                                                \
  do {                                                                    \
    const size_t ko_ = (size_t)(kt) * BKB;                                \
    llds16(gA + ko_,                      ld + (soff));                   \
    llds16(gA + ko_ + (size_t)64 * K_DIM, ld + (soff) + 8192);            \
    llds16(gB + ko_,                      ld + (soff) + A_BYTES);         \
  } while (0)
#define STAGE_P1(kt, soff)                                                \
  do {                                                                    \
    const size_t ko_ = (size_t)(kt) * BKB;                                \
    llds16(gB + ko_ + (size_t)64  * K_DIM, ld + (soff) + A_BYTES + 8192); \
    llds16(gB + ko_ + (size_t)128 * K_DIM, ld + (soff) + A_BYTES + 16384);\
    llds16(gB + ko_ + (size_t)192 * K_DIM, ld + (soff) + A_BYTES + 24576);\
  } while (0)

  // ---- fragment map (R1/R2-proven lane rules): lane l -> row l&15 (+16*frag),
  // 16B chunk kc = l>>4 within the 64B k-step; seg_phys = seg_log ^ (row&7).
  const int lane = tid & 63;
  const int wid = tid >> 6;
  const int wm = wid >> 2;   // 0..1 -> 64-row half of the 128 rows
  const int wn = wid & 3;    // 0..3 -> 64-col quarter of the 256 cols
  const int l15 = lane & 15;
  const int kc = lane >> 4;
  const int sx0 = ((0 + kc) ^ (l15 & 7)) * 16;  // k-step 0 seg offset
  const int sx1 = ((4 + kc) ^ (l15 & 7)) * 16;  // k-step 1 seg offset
  const int offA = (wm * 64 + l15) * BKB;            // + m*2048
  const int offB = A_BYTES + (wn * 64 + l15) * BKB;  // + n*2048

  v4i acc[4][4] = {};

  // one phase: ds_read 8 frags (+ staging issued by caller before this),
  // barrier, lgkmcnt(0), prio1, 16 MFMA, prio0.
#define CPHASE(roff, sx)                                                     \
  do {                                                                       \
    const signed char* bp_ = smem + (roff);                                  \
    v4i a_[4], b_[4];                                                        \
    _Pragma("unroll")                                                        \
    for (int m_ = 0; m_ < 4; ++m_)                                           \
      a_[m_] = *reinterpret_cast<const v4i*>(bp_ + offA + m_ * 2048 + (sx)); \
    _Pragma("unroll")                                                        \
    for (int n_ = 0; n_ < 4; ++n_)                                           \
      b_[n_] = *reinterpret_cast<const v4i*>(bp_ + offB + n_ * 2048 + (sx)); \
    __builtin_amdgcn_s_barrier();                                            \
    asm volatile("s_waitcnt lgkmcnt(0)" ::: "memory");                       \
    __builtin_amdgcn_sched_barrier(0);                                       \
    __builtin_amdgcn_s_setprio(1);                                           \
    _Pragma("unroll")                                                        \
    for (int m_ = 0; m_ < 4; ++m_)                                           \
      _Pragma("unroll")                                                      \
      for (int n_ = 0; n_ < 4; ++n_)                                         \
        acc[m_][n_] = __builtin_amdgcn_mfma_i32_16x16x64_i8(                 \
            a_[m_], b_[n_], acc[m_][n_], 0, 0, 0);                           \
    __builtin_amdgcn_s_setprio(0);                                           \
  } while (0)

  // prologue: tiles 0,1 fully staged (12 loads in flight/thread)
  STAGE_P0(0, 0);
  STAGE_P1(0, 0);
  STAGE_P0(1, TILE3_B);
  STAGE_P1(1, TILE3_B);
  asm volatile("s_waitcnt vmcnt(6)" ::: "memory");  // retire tile 0
  __builtin_amdgcn_s_barrier();

  int rOff = 0;
  int sOff = 2 * TILE3_B;
  for (int t = 0; t < NT3 - 2; ++t) {
    // phase 0: k-step 0 || stage half of tile t+2
    STAGE_P0(t + 2, sOff);
    CPHASE(rOff, sx0);
    __builtin_amdgcn_s_barrier();
    // phase 1: k-step 1 || stage rest of tile t+2
    STAGE_P1(t + 2, sOff);
    CPHASE(rOff, sx1);
    // gate tile t+1 (outstanding: t+1:6, t+2:6 = 12 -> retire t+1)
    asm volatile("s_waitcnt vmcnt(6)" ::: "memory");
    __builtin_amdgcn_s_barrier();
    rOff = (rOff == 2 * TILE3_B) ? 0 : rOff + TILE3_B;
    sOff = (sOff == 2 * TILE3_B) ? 0 : sOff + TILE3_B;
  }
  // iter NT3-2: no staging; gate last tile with vmcnt(0)
  CPHASE(rOff, sx0);
  __builtin_amdgcn_s_barrier();
  CPHASE(rOff, sx1);
  asm volatile("s_waitcnt vmcnt(0)" ::: "memory");
  __builtin_amdgcn_s_barrier();
  rOff = (rOff == 2 * TILE3_B) ? 0 : rOff + TILE3_B;
  // iter NT3-1: final tile
  CPHASE(rOff, sx0);
  __builtin_amdgcn_s_barrier();
  CPHASE(rOff, sx1);

#undef STAGE_P0
#undef STAGE_P1
#undef CPHASE

  // epilogue: C/D 16x16 layout col=lane&15, row=(lane>>4)*4+reg (proven)
  const float s = scales[1];
#pragma unroll
  for (int n = 0; n < 4; ++n) {
    const int col = n0 + wn * 64 + n * 16 + l15;
    const float bv = bias[col];
#pragma unroll
    for (int m = 0; m < 4; ++m) {
      const int r0 = m0 + wm * 64 + m * 16 + kc * 4;
#pragma unroll
      for (int j = 0; j < 4; ++j)
        y[(size_t)(r0 + j) * N_DIM + col] = (float)acc[m][n][j] * s + bv;
    }
  }
}

// ---------------- fallback (small ws): sdot4 LDS GEMM reading w32 ----------------
#if defined(__has_builtin)
#if __has_builtin(__builtin_amdgcn_sdot4)
#define HAVE_SDOT4 1
#endif
#endif

static __device__ __forceinline__ int dot4(int a, int b, int c) {
#ifdef HAVE_SDOT4
  return __builtin_amdgcn_sdot4(a, b, c, false);
#else
  c += (int)(signed char)(a) * (int)(signed char)(b);
  c += (int)(signed char)(a >> 8) * (int)(signed char)(b >> 8);
  c += (int)(signed char)(a >> 16) * (int)(signed char)(b >> 16);
  c += (int)(signed char)(a >> 24) * (int)(signed char)(b >> 24);
  return c;
#endif
}

__global__ __launch_bounds__(256) void gemm_fallback(
    const signed char* __restrict__ xq, const int* __restrict__ w,
    const float* __restrict__ scales, const float* __restrict__ bias,
    float* __restrict__ y) {
  __shared__ int lds_a[64 * 17];
  __shared__ int lds_b[64 * 17];
  const int t = threadIdx.x;
  const int m0 = blockIdx.y * 64;
  const int n0 = blockIdx.x * 64;
  const int my = (t >> 4) * 4;
  const int nx = (t & 15) * 4;
  int acc[4][4] = {};
  for (int kt = 0; kt < K_DIM / 64; ++kt) {
    const int k0 = kt * 64;
    {
      const int r = t >> 2, sg = t & 3;
      v4i v = *reinterpret_cast<const v4i*>(xq + (size_t)(m0 + r) * K_DIM + k0 + sg * 16);
      lds_a[r * 17 + sg * 4 + 0] = v[0];
      lds_a[r * 17 + sg * 4 + 1] = v[1];
      lds_a[r * 17 + sg * 4 + 2] = v[2];
      lds_a[r * 17 + sg * 4 + 3] = v[3];
    }
    {
      const int n = t & 63, bkk = (t >> 6) * 4;
#pragma unroll
      for (int q = 0; q < 4; ++q) {
        const int kk = bkk + q;
        int b0 = w[(size_t)(k0 + kk * 4 + 0) * N_DIM + n0 + n] & 255;
        int b1 = w[(size_t)(k0 + kk * 4 + 1) * N_DIM + n0 + n] & 255;
        int b2 = w[(size_t)(k0 + kk * 4 + 2) * N_DIM + n0 + n] & 255;
        int b3 = w[(size_t)(k0 + kk * 4 + 3) * N_DIM + n0 + n] & 255;
        lds_b[n * 17 + kk] = b0 | (b1 << 8) | (b2 << 16) | (b3 << 24);
      }
    }
    __syncthreads();
#pragma unroll
    for (int kk = 0; kk < 16; ++kk) {
      int a[4], b[4];
#pragma unroll
      for (int i = 0; i < 4; ++i) a[i] = lds_a[(my + i) * 17 + kk];
#pragma unroll
      for (int j = 0; j < 4; ++j) b[j] = lds_b[(nx + j) * 17 + kk];
#pragma unroll
      for (int i = 0; i < 4; ++i)
#pragma unroll
        for (int j = 0; j < 4; ++j) acc[i][j] = dot4(a[i], b[j], acc[i][j]);
    }
    __syncthreads();
  }
  const float s = scales[1];
#pragma unroll
  for (int i = 0; i < 4; ++i)
#pragma unroll
    for (int j = 0; j < 4; ++j)
      y[(size_t)(m0 + my + i) * N_DIM + n0 + nx + j] =
          (float)acc[i][j] * s + bias[n0 + nx + j];
}

// ---------------- launcher ----------------
extern "C" void kernel_launch(void* const* d_in, const int* in_sizes, int n_in,
                              void* d_out, int out_size, void* d_ws, size_t ws_size,
                              hipStream_t stream) {
  (void)in_sizes; (void)n_in; (void)out_size;
  const float* x = (const float*)d_in[0];
  const int* w = (const int*)d_in[1];  // int8 values stored as int32
  const float* bias = (const float*)d_in[2];
  const float* yscale = (const float*)d_in[3];
  float* y = (float*)d_out;
  char* ws = (char*)d_ws;
  float* scales = (float*)(ws);
  float* part = (float*)(ws + 1024);
  signed char* xq = (signed char*)(ws + WS_XQ_OFF);
  signed char* wt = (signed char*)(ws + WS_WT_OFF);

  if (ws_size < WS_SMALL_BYTES) return;

  absmax_kernel<<<1024, 256, 0, stream>>>(x, part);
  finalize_scale<<<1, 256, 0, stream>>>(part, yscale, scales);
  quant_kernel<<<2048, 256, 0, stream>>>(x, scales, xq);
  if (ws_size >= WS_FULL_BYTES) {
    transpose_pack<<<dim3(N_DIM / 64, K_DIM / 64), 256, 0, stream>>>(w, wt);
    gemm_i8_v3<<<(M_DIM / 128) * (N_DIM / 256), 512, 0, stream>>>(xq, wt, scales, bias, y);
  } else {
    gemm_fallback<<<dim3(N_DIM / 64, M_DIM / 64), 256, 0, stream>>>(xq, w, scales, bias, y);
  }
}

// Round 4
// 169.332 us; speedup vs baseline: 1.0271x; 1.0271x over previous
//
#include <hip/hip_runtime.h>
#include <stdint.h>

#define M_DIM 2048
#define K_DIM 4096
#define N_DIM 11008

typedef int v4i __attribute__((ext_vector_type(4)));

// ---------------- workspace layout ----------------
#define WS_XQ_OFF   65536ull
#define WS_WT_OFF   8454144ull
#define WS_FULL_BYTES (8454144ull + 45088768ull)
#define WS_SMALL_BYTES 8454144ull

static __device__ __forceinline__ void llds16(const void* g, void* l) {
  __builtin_amdgcn_global_load_lds(
      reinterpret_cast<const uint32_t __attribute__((address_space(1)))*>(
          reinterpret_cast<uintptr_t>(g)),
      reinterpret_cast<uint32_t __attribute__((address_space(3)))*>(
          reinterpret_cast<uintptr_t>(l)),
      16, 0, 0);
}

// ---------------- kernel 1: per-block abs-max over x ----------------
__global__ __launch_bounds__(256) void absmax_kernel(const float* __restrict__ x,
                                                     float* __restrict__ part) {
  __shared__ float red[256];
  const int g = blockIdx.x * 256 + threadIdx.x;
  const float4* x4 = reinterpret_cast<const float4*>(x);
  float m = 0.f;
#pragma unroll
  for (int i = 0; i < 8; ++i) {
    float4 v = x4[(size_t)i * 262144 + g];
    m = fmaxf(m, fmaxf(fmaxf(fabsf(v.x), fabsf(v.y)),
                       fmaxf(fabsf(v.z), fabsf(v.w))));
  }
  red[threadIdx.x] = m;
  __syncthreads();
  for (int s = 128; s > 0; s >>= 1) {
    if (threadIdx.x < s) red[threadIdx.x] = fmaxf(red[threadIdx.x], red[threadIdx.x + s]);
    __syncthreads();
  }
  if (threadIdx.x == 0) part[blockIdx.x] = red[0];
}

// ---------------- kernel 2: finalize scales ----------------
__global__ __launch_bounds__(256) void finalize_scale(const float* __restrict__ part,
                                                      const float* __restrict__ y_scale,
                                                      float* __restrict__ scales) {
  __shared__ float red[256];
  const int t = threadIdx.x;
  float m = fmaxf(fmaxf(part[t], part[t + 256]), fmaxf(part[t + 512], part[t + 768]));
  red[t] = m;
  __syncthreads();
  for (int s = 128; s > 0; s >>= 1) {
    if (t < s) red[t] = fmaxf(red[t], red[t + s]);
    __syncthreads();
  }
  if (t == 0) {
    float xs = red[0] * (1.0f / 128.0f);  // exact (pow2)
    scales[0] = xs;
    scales[1] = xs * y_scale[0];
  }
}

// ---------------- kernel 3: quantize x -> int8 ----------------
__global__ __launch_bounds__(256) void quant_kernel(const float* __restrict__ x,
                                                    const float* __restrict__ scales,
                                                    signed char* __restrict__ xq) {
  const float s = scales[0];
  const size_t t = (size_t)blockIdx.x * 256 + threadIdx.x;
  const float4* x4 = reinterpret_cast<const float4*>(x) + t * 4;
  v4i o;
#pragma unroll
  for (int i = 0; i < 4; ++i) {
    float4 v = x4[i];
    int q0 = (int)rintf(v.x / s);  // matches np.round (half-to-even)
    int q1 = (int)rintf(v.y / s);
    int q2 = (int)rintf(v.z / s);
    int q3 = (int)rintf(v.w / s);
    q0 = max(-128, min(127, q0));
    q1 = max(-128, min(127, q1));
    q2 = max(-128, min(127, q2));
    q3 = max(-128, min(127, q3));
    o[i] = (q0 & 255) | ((q1 & 255) << 8) | ((q2 & 255) << 16) | ((q3 & 255) << 24);
  }
  *reinterpret_cast<v4i*>(xq + t * 16) = o;
}

// ---------------- kernel 4: transpose+pack w32[K,N] -> w_t int8[N,K] ----------------
__global__ __launch_bounds__(256) void transpose_pack(const int* __restrict__ w,
                                                      signed char* __restrict__ wt) {
  __shared__ int tile[64 * 65];
  const int t = threadIdx.x;
  const int n0 = blockIdx.x * 64;
  const int k0 = blockIdx.y * 64;
#pragma unroll
  for (int p = 0; p < 4; ++p) {
    const int id = p * 256 + t;
    const int r = id >> 4;
    const int c4 = id & 15;
    v4i v = *reinterpret_cast<const v4i*>(w + (size_t)(k0 + r) * N_DIM + n0 + c4 * 4);
    tile[r * 65 + c4 * 4 + 0] = v[0];
    tile[r * 65 + c4 * 4 + 1] = v[1];
    tile[r * 65 + c4 * 4 + 2] = v[2];
    tile[r * 65 + c4 * 4 + 3] = v[3];
  }
  __syncthreads();
  const int nl = t >> 2;
  const int kseg = t & 3;
  v4i o;
#pragma unroll
  for (int q = 0; q < 4; ++q) {
    const int kb = kseg * 16 + q * 4;
    int b0 = tile[(kb + 0) * 65 + nl] & 255;
    int b1 = tile[(kb + 1) * 65 + nl] & 255;
    int b2 = tile[(kb + 2) * 65 + nl] & 255;
    int b3 = tile[(kb + 3) * 65 + nl] & 255;
    o[q] = b0 | (b1 << 8) | (b2 << 16) | (b3 << 24);
  }
  *reinterpret_cast<v4i*>(wt + (size_t)(n0 + nl) * K_DIM + k0 + kseg * 16) = o;
}

// ---------------- kernel 5: int8 MFMA GEMM v4 (occupancy-first) ----------------
// BM=128, BN=256, BK=64 bytes. 512 threads = 8 waves (2M x 4N), wave-tile
// 64x64 via 4x4 frags of mfma_i32_16x16x64_i8 (R1-proven maps).
// Ring-3 LDS = 3 x 24KB = 72KB -> 2 blocks/CU = 16 waves/CU (4 waves/SIMD).
// Depth-2 prefetch, vmcnt(3) once per K-tile, single barrier per K-tile;
// latency hiding via cross-block wave mixing (m114), not hand phases.
#define V4_TILE_B 24576           // A 128x64 (8KB) + B 256x64 (16KB)
#define V4_NT     (K_DIM / 64)    // 64 K-tiles

__global__ __launch_bounds__(512, 4) void gemm_i8_v4(
    const signed char* __restrict__ xq, const signed char* __restrict__ wt,
    const float* __restrict__ scales, const float* __restrict__ bias,
    float* __restrict__ y) {
  __shared__ __align__(16) signed char smem[3 * V4_TILE_B];  // 72 KB
  const int tid = threadIdx.x;

  // T1: bijective XCD swizzle (688 blocks, 688 % 8 == 0), column-major grid
  // (16 m-tiles share each 1MB wt n-panel in L2).
  const int bid = blockIdx.x;
  const int swz = (bid & 7) * 86 + (bid >> 3);
  const int m0 = (swz & 15) * 128;
  const int n0 = (swz >> 4) * 256;

  // ---- staging map: thread -> (row = tid>>2, seg = tid&3) of a 64B row.
  // LDS dest linear (slot = row*4+seg = tid); XOR involution
  // seg' = seg ^ ((row>>1)&3) applied on the GLOBAL source (both-sides rule).
  // K-offsets (kt*64) move along the row -> row bits unchanged -> k-invariant.
  const int srow = tid >> 2;   // 0..127
  const int sseg = tid & 3;
  const int sgoff = (sseg ^ ((srow >> 1) & 3)) * 16;
  const signed char* gA  = xq + (size_t)(m0 + srow) * K_DIM + sgoff;
  const signed char* gB0 = wt + (size_t)(n0 + srow) * K_DIM + sgoff;
  const signed char* gB1 = wt + (size_t)(n0 + 128 + srow) * K_DIM + sgoff;
  signed char* const ldA  = smem + tid * 16;           // A: [0, 8192)
  signed char* const ldB0 = smem + 8192 + tid * 16;    // B rows 0..127
  signed char* const ldB1 = smem + 16384 + tid * 16;   // B rows 128..255

#define STAGE(kt, soff)                                   \
  do {                                                    \
    const size_t ko_ = (size_t)(kt) * 64;                 \
    llds16(gA + ko_,  ldA + (soff));                      \
    llds16(gB0 + ko_, ldB0 + (soff));                     \
    llds16(gB1 + ko_, ldB1 + (soff));                     \
  } while (0)

  // ---- fragment map (R1-proven lane rules, 64B rows): lane l -> row l&15
  // (+16*frag), 16B chunk kc = l>>4; seg_phys = kc ^ ((row>>1)&3).
  // Frag row offsets (wm*64, m*16) are 0 mod 8 -> swizzle depends on l15 only.
  const int lane = tid & 63;
  const int wid = tid >> 6;
  const int wm = wid >> 2;   // 0..1 -> 64-row half of 128
  const int wn = wid & 3;    // 0..3 -> 64-col quarter of 256
  const int l15 = lane & 15;
  const int kc = lane >> 4;
  const int segoff = (kc ^ ((l15 >> 1) & 3)) * 16;
  const int offA = (wm * 64 + l15) * 64 + segoff;          // + m*1024
  const int offB = 8192 + (wn * 64 + l15) * 64 + segoff;   // + n*1024

  v4i acc[4][4] = {};

#define COMPUTE(roff)                                                        \
  do {                                                                       \
    const signed char* bp_ = smem + (roff);                                  \
    v4i a_[4], b_[4];                                                        \
    _Pragma("unroll")                                                        \
    for (int m_ = 0; m_ < 4; ++m_)                                           \
      a_[m_] = *reinterpret_cast<const v4i*>(bp_ + offA + m_ * 1024);        \
    _Pragma("unroll")                                                        \
    for (int n_ = 0; n_ < 4; ++n_)                                           \
      b_[n_] = *reinterpret_cast<const v4i*>(bp_ + offB + n_ * 1024);        \
    _Pragma("unroll")                                                        \
    for (int m_ = 0; m_ < 4; ++m_)                                           \
      _Pragma("unroll")                                                      \
      for (int n_ = 0; n_ < 4; ++n_)                                         \
        acc[m_][n_] = __builtin_amdgcn_mfma_i32_16x16x64_i8(                 \
            a_[m_], b_[n_], acc[m_][n_], 0, 0, 0);                           \
  } while (0)

  // prologue: stage tiles 0,1 (6 loads/thread in flight)
  STAGE(0, 0);
  STAGE(1, V4_TILE_B);
  asm volatile("s_waitcnt vmcnt(3)" ::: "memory");  // tile 0 landed
  __builtin_amdgcn_s_barrier();

  int rOff = 0;
  int sOff = 2 * V4_TILE_B;
  for (int t = 0; t < V4_NT - 2; ++t) {
    STAGE(t + 2, sOff);              // outstanding: t+1:3, t+2:3
    COMPUTE(rOff);                   // 8 ds_read_b128 + 16 MFMA (compiler-sched)
    asm volatile("s_waitcnt vmcnt(3)" ::: "memory");  // retire tile t+1
    __builtin_amdgcn_s_barrier();
    rOff = (rOff == 2 * V4_TILE_B) ? 0 : rOff + V4_TILE_B;
    sOff = (sOff == 2 * V4_TILE_B) ? 0 : sOff + V4_TILE_B;
  }
  // t = NT-2: no staging; drain remaining tile
  COMPUTE(rOff);
  asm volatile("s_waitcnt vmcnt(0)" ::: "memory");
  __builtin_amdgcn_s_barrier();
  rOff = (rOff == 2 * V4_TILE_B) ? 0 : rOff + V4_TILE_B;
  // t = NT-1: final tile
  COMPUTE(rOff);

#undef STAGE
#undef COMPUTE

  // epilogue: C/D 16x16 layout col=lane&15, row=(lane>>4)*4+reg (R1-proven)
  const float s = scales[1];
#pragma unroll
  for (int n = 0; n < 4; ++n) {
    const int col = n0 + wn * 64 + n * 16 + l15;
    const float bv = bias[col];
#pragma unroll
    for (int m = 0; m < 4; ++m) {
      const int r0 = m0 + wm * 64 + m * 16 + kc * 4;
#pragma unroll
      for (int j = 0; j < 4; ++j)
        y[(size_t)(r0 + j) * N_DIM + col] = (float)acc[m][n][j] * s + bv;
    }
  }
}

// ---------------- fallback (small ws): sdot4 LDS GEMM reading w32 ----------------
#if defined(__has_builtin)
#if __has_builtin(__builtin_amdgcn_sdot4)
#define HAVE_SDOT4 1
#endif
#endif

static __device__ __forceinline__ int dot4(int a, int b, int c) {
#ifdef HAVE_SDOT4
  return __builtin_amdgcn_sdot4(a, b, c, false);
#else
  c += (int)(signed char)(a) * (int)(signed char)(b);
  c += (int)(signed char)(a >> 8) * (int)(signed char)(b >> 8);
  c += (int)(signed char)(a >> 16) * (int)(signed char)(b >> 16);
  c += (int)(signed char)(a >> 24) * (int)(signed char)(b >> 24);
  return c;
#endif
}

__global__ __launch_bounds__(256) void gemm_fallback(
    const signed char* __restrict__ xq, const int* __restrict__ w,
    const float* __restrict__ scales, const float* __restrict__ bias,
    float* __restrict__ y) {
  __shared__ int lds_a[64 * 17];
  __shared__ int lds_b[64 * 17];
  const int t = threadIdx.x;
  const int m0 = blockIdx.y * 64;
  const int n0 = blockIdx.x * 64;
  const int my = (t >> 4) * 4;
  const int nx = (t & 15) * 4;
  int acc[4][4] = {};
  for (int kt = 0; kt < K_DIM / 64; ++kt) {
    const int k0 = kt * 64;
    {
      const int r = t >> 2, sg = t & 3;
      v4i v = *reinterpret_cast<const v4i*>(xq + (size_t)(m0 + r) * K_DIM + k0 + sg * 16);
      lds_a[r * 17 + sg * 4 + 0] = v[0];
      lds_a[r * 17 + sg * 4 + 1] = v[1];
      lds_a[r * 17 + sg * 4 + 2] = v[2];
      lds_a[r * 17 + sg * 4 + 3] = v[3];
    }
    {
      const int n = t & 63, bkk = (t >> 6) * 4;
#pragma unroll
      for (int q = 0; q < 4; ++q) {
        const int kk = bkk + q;
        int b0 = w[(size_t)(k0 + kk * 4 + 0) * N_DIM + n0 + n] & 255;
        int b1 = w[(size_t)(k0 + kk * 4 + 1) * N_DIM + n0 + n] & 255;
        int b2 = w[(size_t)(k0 + kk * 4 + 2) * N_DIM + n0 + n] & 255;
        int b3 = w[(size_t)(k0 + kk * 4 + 3) * N_DIM + n0 + n] & 255;
        lds_b[n * 17 + kk] = b0 | (b1 << 8) | (b2 << 16) | (b3 << 24);
      }
    }
    __syncthreads();
#pragma unroll
    for (int kk = 0; kk < 16; ++kk) {
      int a[4], b[4];
#pragma unroll
      for (int i = 0; i < 4; ++i) a[i] = lds_a[(my + i) * 17 + kk];
#pragma unroll
      for (int j = 0; j < 4; ++j) b[j] = lds_b[(nx + j) * 17 + kk];
#pragma unroll
      for (int i = 0; i < 4; ++i)
#pragma unroll
        for (int j = 0; j < 4; ++j) acc[i][j] = dot4(a[i], b[j], acc[i][j]);
    }
    __syncthreads();
  }
  const float s = scales[1];
#pragma unroll
  for (int i = 0; i < 4; ++i)
#pragma unroll
    for (int j = 0; j < 4; ++j)
      y[(size_t)(m0 + my + i) * N_DIM + n0 + nx + j] =
          (float)acc[i][j] * s + bias[n0 + nx + j];
}

// ---------------- launcher ----------------
extern "C" void kernel_launch(void* const* d_in, const int* in_sizes, int n_in,
                              void* d_out, int out_size, void* d_ws, size_t ws_size,
                              hipStream_t stream) {
  (void)in_sizes; (void)n_in; (void)out_size;
  const float* x = (const float*)d_in[0];
  const int* w = (const int*)d_in[1];  // int8 values stored as int32
  const float* bias = (const float*)d_in[2];
  const float* yscale = (const float*)d_in[3];
  float* y = (float*)d_out;
  char* ws = (char*)d_ws;
  float* scales = (float*)(ws);
  float* part = (float*)(ws + 1024);
  signed char* xq = (signed char*)(ws + WS_XQ_OFF);
  signed char* wt = (signed char*)(ws + WS_WT_OFF);

  if (ws_size < WS_SMALL_BYTES) return;

  absmax_kernel<<<1024, 256, 0, stream>>>(x, part);
  finalize_scale<<<1, 256, 0, stream>>>(part, yscale, scales);
  quant_kernel<<<2048, 256, 0, stream>>>(x, scales, xq);
  if (ws_size >= WS_FULL_BYTES) {
    transpose_pack<<<dim3(N_DIM / 64, K_DIM / 64), 256, 0, stream>>>(w, wt);
    gemm_i8_v4<<<(M_DIM / 128) * (N_DIM / 256), 512, 0, stream>>>(xq, wt, scales, bias, y);
  } else {
    gemm_fallback<<<dim3(N_DIM / 64, M_DIM / 64), 256, 0, stream>>>(xq, w, scales, bias, y);
  }
}